// Round 1
// baseline (1723.795 us; speedup 1.0000x reference)
//
#include <hip/hip_runtime.h>
#include <cstdint>

// Problem constants
#define B_    4
#define T_    2048
#define DIM_  1024
#define H_    16
#define N_    64
#define BT_   8192   // B_*T_

__device__ __forceinline__ float silu_f(float v) {
    // v * sigmoid(v); robust for |v| large
    return v / (1.f + __expf(-v));
}
__device__ __forceinline__ float tanh_f(float v) {
    // tanh(v) = 1 - 2/(exp(2v)+1); robust for |v| large
    return 1.f - 2.f / (__expf(2.f * v) + 1.f);
}

// -------------------------------------------------------------------------
// K1: xz = X @ W_in^T  (M=8192, K=1024, N=2048), 64x64 tile, 4x4/thread.
// Epilogue: silu; cols <1024 additionally multiplied by per-head W_x (64x64)
// via LDS staging. Outputs written in [B,H,T,N] layout for the scan.
// grid = (32 n-tiles, 128 m-tiles), block = 256
// -------------------------------------------------------------------------
__global__ __launch_bounds__(256) void gemm_in_kernel(
    const float* __restrict__ X,    // [8192,1024]
    const float* __restrict__ Win,  // [2048,1024]
    const float* __restrict__ Wx,   // [16,64,64]
    float* __restrict__ preX,       // [B,H,T,N]
    float* __restrict__ gate)       // [B,H,T,N]
{
    __shared__ float As[16][68];
    __shared__ float Bs[16][68];
    __shared__ float sT[64][65];
    __shared__ float Wxs[64][64];

    const int tid = threadIdx.x;
    const int tx = tid & 15, ty = tid >> 4;
    const int m0 = blockIdx.y * 64;
    const int n0 = blockIdx.x * 64;
    const int lr = tid >> 2;          // 0..63
    const int lc = (tid & 3) << 2;    // 0,4,8,12

    const float* Ap = X + (size_t)(m0 + lr) * 1024 + lc;
    const float* Bp = Win + (size_t)(n0 + lr) * 1024 + lc;

    float acc[4][4] = {};

    for (int k0 = 0; k0 < 1024; k0 += 16) {
        float4 av = *(const float4*)(Ap + k0);
        float4 bv = *(const float4*)(Bp + k0);
        __syncthreads();
        As[lc + 0][lr] = av.x; As[lc + 1][lr] = av.y;
        As[lc + 2][lr] = av.z; As[lc + 3][lr] = av.w;
        Bs[lc + 0][lr] = bv.x; Bs[lc + 1][lr] = bv.y;
        Bs[lc + 2][lr] = bv.z; Bs[lc + 3][lr] = bv.w;
        __syncthreads();
        #pragma unroll
        for (int kk = 0; kk < 16; ++kk) {
            float4 a4 = *(const float4*)&As[kk][ty << 2];
            float4 b4 = *(const float4*)&Bs[kk][tx << 2];
            float ar[4] = {a4.x, a4.y, a4.z, a4.w};
            float br[4] = {b4.x, b4.y, b4.z, b4.w};
            #pragma unroll
            for (int r = 0; r < 4; ++r)
                #pragma unroll
                for (int c = 0; c < 4; ++c)
                    acc[r][c] = fmaf(ar[r], br[c], acc[r][c]);
        }
    }

    float s[4][4];
    #pragma unroll
    for (int r = 0; r < 4; ++r)
        #pragma unroll
        for (int c = 0; c < 4; ++c)
            s[r][c] = silu_f(acc[r][c]);

    if (blockIdx.x >= 16) {
        // gate half: store silu(z) directly in [B,H,T,N]
        const int h = blockIdx.x - 16;
        #pragma unroll
        for (int r = 0; r < 4; ++r) {
            int m = m0 + (ty << 2) + r;
            int b = m >> 11, t = m & 2047;
            float4 o = make_float4(s[r][0], s[r][1], s[r][2], s[r][3]);
            *(float4*)(gate + ((((b << 4) + h) * 2048 + t) << 6) + (tx << 2)) = o;
        }
    } else {
        // x half: pre_x = silu(x_proj) @ W_x[h]
        const int h = blockIdx.x;
        #pragma unroll
        for (int r = 0; r < 4; ++r)
            #pragma unroll
            for (int c = 0; c < 4; ++c)
                sT[(ty << 2) + r][(tx << 2) + c] = s[r][c];
        const float4* wsrc = (const float4*)(Wx + (h << 12));
        float4* wdst = (float4*)&Wxs[0][0];
        #pragma unroll
        for (int q = 0; q < 4; ++q)
            wdst[q * 256 + tid] = wsrc[q * 256 + tid];
        __syncthreads();
        float acc2[4][4] = {};
        #pragma unroll
        for (int i = 0; i < 64; ++i) {
            float ar[4];
            ar[0] = sT[(ty << 2) + 0][i];
            ar[1] = sT[(ty << 2) + 1][i];
            ar[2] = sT[(ty << 2) + 2][i];
            ar[3] = sT[(ty << 2) + 3][i];
            float4 w4 = *(const float4*)&Wxs[i][tx << 2];
            float wr[4] = {w4.x, w4.y, w4.z, w4.w};
            #pragma unroll
            for (int r = 0; r < 4; ++r)
                #pragma unroll
                for (int c = 0; c < 4; ++c)
                    acc2[r][c] = fmaf(ar[r], wr[c], acc2[r][c]);
        }
        #pragma unroll
        for (int r = 0; r < 4; ++r) {
            int m = m0 + (ty << 2) + r;
            int b = m >> 11, t = m & 2047;
            float4 o = make_float4(acc2[r][0], acc2[r][1], acc2[r][2], acc2[r][3]);
            *(float4*)(preX + ((((b << 4) + h) * 2048 + t) << 6) + (tx << 2)) = o;
        }
    }
}

// -------------------------------------------------------------------------
// K2: sequential Elman scan. One wave (64 threads) per (b,h) pair.
// Lane j computes h_new[j]; full h replicated in registers on every lane,
// rebuilt each step via LDS broadcast (single-wave lockstep => no barrier).
// out = h_new * gate overwrites the gate buffer in place ([B,H,T,N]).
// grid = 64, block = 64
// -------------------------------------------------------------------------
__global__ __launch_bounds__(64) void scan_kernel(
    const float* __restrict__ preX,  // [B,H,T,N]
    float* __restrict__ og,          // in: gate, out: h*g, [B,H,T,N]
    const float* __restrict__ Wh,    // [16,64,64]
    const float* __restrict__ bias,  // [16,64]
    const float* __restrict__ h0,    // [B,H,N]
    float* __restrict__ hfin)        // [B,H,N]
{
    const int bh = blockIdx.x;       // b*16 + h
    const int h = bh & 15;
    const int j = threadIdx.x;
    __shared__ float sh[64];

    float w[64];
    #pragma unroll
    for (int i = 0; i < 64; ++i)
        w[i] = Wh[(h << 12) + (i << 6) + j];   // W_h[h][i][j]
    const float bj = bias[(h << 6) + j];

    sh[j] = h0[(bh << 6) + j];
    __syncthreads();
    float hr[64];
    #pragma unroll
    for (int i = 0; i < 16; ++i) {
        float4 v = *(const float4*)&sh[i << 2];
        hr[(i << 2) + 0] = v.x; hr[(i << 2) + 1] = v.y;
        hr[(i << 2) + 2] = v.z; hr[(i << 2) + 3] = v.w;
    }

    const float* px_p = preX + ((size_t)bh << 17);   // bh * T_*N_
    float* og_p = og + ((size_t)bh << 17);

    // distance-2 prefetch
    float pxA = px_p[j],      gA = og_p[j];
    float pxB = px_p[64 + j], gB = og_p[64 + j];

    float hn = 0.f;
    for (int t = 0; t < T_; ++t) {
        float px = pxA, g = gA;
        pxA = pxB; gA = gB;
        if (t + 2 < T_) {
            pxB = px_p[((t + 2) << 6) + j];
            gB  = og_p[((t + 2) << 6) + j];
        }
        float a0 = px + bj, a1 = 0.f, a2 = 0.f, a3 = 0.f;
        #pragma unroll
        for (int i = 0; i < 64; i += 4) {
            a0 = fmaf(hr[i + 0], w[i + 0], a0);
            a1 = fmaf(hr[i + 1], w[i + 1], a1);
            a2 = fmaf(hr[i + 2], w[i + 2], a2);
            a3 = fmaf(hr[i + 3], w[i + 3], a3);
        }
        float a = (a0 + a1) + (a2 + a3);
        hn = tanh_f(a);
        og_p[(t << 6) + j] = hn * g;

        // broadcast h_new to all lanes (single wave: lockstep-ordered)
        __builtin_amdgcn_wave_barrier();
        sh[j] = hn;
        __builtin_amdgcn_wave_barrier();
        #pragma unroll
        for (int i = 0; i < 16; ++i) {
            float4 v = *(const float4*)&sh[i << 2];
            hr[(i << 2) + 0] = v.x; hr[(i << 2) + 1] = v.y;
            hr[(i << 2) + 2] = v.z; hr[(i << 2) + 3] = v.w;
        }
        __builtin_amdgcn_wave_barrier();
    }
    hfin[(bh << 6) + j] = hn;
}

// -------------------------------------------------------------------------
// K3: out = og @ W_out^T (M=8192, K=1024, N=1024), 128x128 tile, 8x8/thread.
// A is read from [B,H,T,N] layout with head-aware indexing.
// grid = (8 n-tiles, 64 m-tiles), block = 256
// -------------------------------------------------------------------------
__global__ __launch_bounds__(256) void gemm_out_kernel(
    const float* __restrict__ og,    // [B,H,T,N] == logical A[8192][1024]
    const float* __restrict__ Wout,  // [1024,1024]
    float* __restrict__ out)         // [8192,1024]
{
    __shared__ float As[16][132];
    __shared__ float Bs[16][132];

    const int tid = threadIdx.x;
    const int tx = tid & 15, ty = tid >> 4;
    const int m0 = blockIdx.y * 128;
    const int n0 = blockIdx.x * 128;
    const int lr = tid >> 1;          // 0..127
    const int lc = (tid & 1) << 3;    // 0 or 8

    const int m = m0 + lr;
    const int b = m >> 11, t = m & 2047;

    float acc[8][8] = {};

    for (int k0 = 0; k0 < 1024; k0 += 16) {
        const int e = k0 + lc;            // logical col in [0,1024)
        const int he = e >> 6, je = e & 63;
        const float* ap = og + ((((b << 4) + he) * 2048 + t) << 6) + je;
        float4 a0v = *(const float4*)(ap);
        float4 a1v = *(const float4*)(ap + 4);
        const float* bp = Wout + (size_t)(n0 + lr) * 1024 + e;
        float4 b0v = *(const float4*)(bp);
        float4 b1v = *(const float4*)(bp + 4);
        __syncthreads();
        As[lc + 0][lr] = a0v.x; As[lc + 1][lr] = a0v.y;
        As[lc + 2][lr] = a0v.z; As[lc + 3][lr] = a0v.w;
        As[lc + 4][lr] = a1v.x; As[lc + 5][lr] = a1v.y;
        As[lc + 6][lr] = a1v.z; As[lc + 7][lr] = a1v.w;
        Bs[lc + 0][lr] = b0v.x; Bs[lc + 1][lr] = b0v.y;
        Bs[lc + 2][lr] = b0v.z; Bs[lc + 3][lr] = b0v.w;
        Bs[lc + 4][lr] = b1v.x; Bs[lc + 5][lr] = b1v.y;
        Bs[lc + 6][lr] = b1v.z; Bs[lc + 7][lr] = b1v.w;
        __syncthreads();
        #pragma unroll
        for (int kk = 0; kk < 16; ++kk) {
            float4 x0 = *(const float4*)&As[kk][ty << 3];
            float4 x1 = *(const float4*)&As[kk][(ty << 3) + 4];
            float4 y0 = *(const float4*)&Bs[kk][tx << 3];
            float4 y1 = *(const float4*)&Bs[kk][(tx << 3) + 4];
            float ar[8] = {x0.x, x0.y, x0.z, x0.w, x1.x, x1.y, x1.z, x1.w};
            float br[8] = {y0.x, y0.y, y0.z, y0.w, y1.x, y1.y, y1.z, y1.w};
            #pragma unroll
            for (int r = 0; r < 8; ++r)
                #pragma unroll
                for (int c = 0; c < 8; ++c)
                    acc[r][c] = fmaf(ar[r], br[c], acc[r][c]);
        }
    }

    #pragma unroll
    for (int r = 0; r < 8; ++r) {
        int mm = m0 + (ty << 3) + r;
        float4 o0 = make_float4(acc[r][0], acc[r][1], acc[r][2], acc[r][3]);
        float4 o1 = make_float4(acc[r][4], acc[r][5], acc[r][6], acc[r][7]);
        *(float4*)(out + (size_t)mm * 1024 + n0 + (tx << 3)) = o0;
        *(float4*)(out + (size_t)mm * 1024 + n0 + (tx << 3) + 4) = o1;
    }
}

// -------------------------------------------------------------------------
extern "C" void kernel_launch(void* const* d_in, const int* in_sizes, int n_in,
                              void* d_out, int out_size, void* d_ws, size_t ws_size,
                              hipStream_t stream)
{
    const float* x    = (const float*)d_in[0];
    const float* h0   = (const float*)d_in[1];
    const float* Win  = (const float*)d_in[2];
    const float* Wx   = (const float*)d_in[3];
    const float* Wh   = (const float*)d_in[4];
    const float* bias = (const float*)d_in[5];
    const float* Wout = (const float*)d_in[6];

    float* out  = (float*)d_out;
    float* hfin = out + (size_t)BT_ * DIM_;      // h_final after main output

    float* preX = (float*)d_ws;                  // [B,H,T,N] 32 MB
    float* gate = preX + (size_t)BT_ * DIM_;     // [B,H,T,N] 32 MB (becomes h*g)

    gemm_in_kernel<<<dim3(32, 128), 256, 0, stream>>>(x, Win, Wx, preX, gate);
    scan_kernel<<<64, 64, 0, stream>>>(preX, gate, Wh, bias, h0, hfin);
    gemm_out_kernel<<<dim3(8, 64), 256, 0, stream>>>(gate, Wout, out);
}

// Round 2
// 1221.859 us; speedup vs baseline: 1.4108x; 1.4108x over previous
//
#include <hip/hip_runtime.h>
#include <cstdint>

// Problem constants
#define B_    4
#define T_    2048
#define DIM_  1024
#define H_    16
#define N_    64
#define BT_   8192   // B_*T_

typedef float f32x2 __attribute__((ext_vector_type(2)));

__device__ __forceinline__ float silu_f(float v) {
    return v / (1.f + __expf(-v));
}
__device__ __forceinline__ float tanh_f(float v) {
    return 1.f - 2.f / (__expf(2.f * v) + 1.f);
}

// -------------------------------------------------------------------------
// K1: xz = X @ W_in^T  (M=8192, K=1024, N=2048), 64x64 tile, 4x4/thread.
// Epilogue: silu; cols <1024 additionally multiplied by per-head W_x (64x64)
// via LDS staging. Outputs written in [B,H,T,N] layout for the scan.
// grid = (32 n-tiles, 128 m-tiles), block = 256
// -------------------------------------------------------------------------
__global__ __launch_bounds__(256) void gemm_in_kernel(
    const float* __restrict__ X,    // [8192,1024]
    const float* __restrict__ Win,  // [2048,1024]
    const float* __restrict__ Wx,   // [16,64,64]
    float* __restrict__ preX,       // [B,H,T,N]
    float* __restrict__ gate)       // [B,H,T,N]
{
    __shared__ float As[16][68];
    __shared__ float Bs[16][68];
    __shared__ float sT[64][65];
    __shared__ float Wxs[64][64];

    const int tid = threadIdx.x;
    const int tx = tid & 15, ty = tid >> 4;
    const int m0 = blockIdx.y * 64;
    const int n0 = blockIdx.x * 64;
    const int lr = tid >> 2;          // 0..63
    const int lc = (tid & 3) << 2;    // 0,4,8,12

    const float* Ap = X + (size_t)(m0 + lr) * 1024 + lc;
    const float* Bp = Win + (size_t)(n0 + lr) * 1024 + lc;

    float acc[4][4] = {};

    for (int k0 = 0; k0 < 1024; k0 += 16) {
        float4 av = *(const float4*)(Ap + k0);
        float4 bv = *(const float4*)(Bp + k0);
        __syncthreads();
        As[lc + 0][lr] = av.x; As[lc + 1][lr] = av.y;
        As[lc + 2][lr] = av.z; As[lc + 3][lr] = av.w;
        Bs[lc + 0][lr] = bv.x; Bs[lc + 1][lr] = bv.y;
        Bs[lc + 2][lr] = bv.z; Bs[lc + 3][lr] = bv.w;
        __syncthreads();
        #pragma unroll
        for (int kk = 0; kk < 16; ++kk) {
            float4 a4 = *(const float4*)&As[kk][ty << 2];
            float4 b4 = *(const float4*)&Bs[kk][tx << 2];
            float ar[4] = {a4.x, a4.y, a4.z, a4.w};
            float br[4] = {b4.x, b4.y, b4.z, b4.w};
            #pragma unroll
            for (int r = 0; r < 4; ++r)
                #pragma unroll
                for (int c = 0; c < 4; ++c)
                    acc[r][c] = fmaf(ar[r], br[c], acc[r][c]);
        }
    }

    float s[4][4];
    #pragma unroll
    for (int r = 0; r < 4; ++r)
        #pragma unroll
        for (int c = 0; c < 4; ++c)
            s[r][c] = silu_f(acc[r][c]);

    if (blockIdx.x >= 16) {
        // gate half: store silu(z) directly in [B,H,T,N]
        const int h = blockIdx.x - 16;
        #pragma unroll
        for (int r = 0; r < 4; ++r) {
            int m = m0 + (ty << 2) + r;
            int b = m >> 11, t = m & 2047;
            float4 o = make_float4(s[r][0], s[r][1], s[r][2], s[r][3]);
            *(float4*)(gate + ((((b << 4) + h) * 2048 + t) << 6) + (tx << 2)) = o;
        }
    } else {
        // x half: pre_x = silu(x_proj) @ W_x[h]
        const int h = blockIdx.x;
        #pragma unroll
        for (int r = 0; r < 4; ++r)
            #pragma unroll
            for (int c = 0; c < 4; ++c)
                sT[(ty << 2) + r][(tx << 2) + c] = s[r][c];
        const float4* wsrc = (const float4*)(Wx + (h << 12));
        float4* wdst = (float4*)&Wxs[0][0];
        #pragma unroll
        for (int q = 0; q < 4; ++q)
            wdst[q * 256 + tid] = wsrc[q * 256 + tid];
        __syncthreads();
        float acc2[4][4] = {};
        #pragma unroll
        for (int i = 0; i < 64; ++i) {
            float ar[4];
            ar[0] = sT[(ty << 2) + 0][i];
            ar[1] = sT[(ty << 2) + 1][i];
            ar[2] = sT[(ty << 2) + 2][i];
            ar[3] = sT[(ty << 2) + 3][i];
            float4 w4 = *(const float4*)&Wxs[i][tx << 2];
            float wr[4] = {w4.x, w4.y, w4.z, w4.w};
            #pragma unroll
            for (int r = 0; r < 4; ++r)
                #pragma unroll
                for (int c = 0; c < 4; ++c)
                    acc2[r][c] = fmaf(ar[r], wr[c], acc2[r][c]);
        }
        #pragma unroll
        for (int r = 0; r < 4; ++r) {
            int m = m0 + (ty << 2) + r;
            int b = m >> 11, t = m & 2047;
            float4 o = make_float4(acc2[r][0], acc2[r][1], acc2[r][2], acc2[r][3]);
            *(float4*)(preX + ((((b << 4) + h) * 2048 + t) << 6) + (tx << 2)) = o;
        }
    }
}

// -------------------------------------------------------------------------
// K2: sequential Elman scan. One wave (64 threads) per (b,h) pair.
// Lane j computes h_new[j]. h broadcast via LDS (single-wave lockstep, no
// barrier needed; LDS pipe is in-order per wave). Deep prefetch: 8-slot
// statically-indexed ring buffer (loop unrolled by 8) so the global load for
// step t+8 is issued at step t — ~2000 cycles of cover vs ~900 cyc HBM
// latency. Dot product as f32x2 packed ops (v_pk_fma_f32) to halve VALU
// issue count at 1 wave/SIMD.
// grid = 64, block = 64
// -------------------------------------------------------------------------
__global__ __launch_bounds__(64) void scan_kernel(
    const float* __restrict__ preX,  // [B,H,T,N]
    float* __restrict__ og,          // in: gate, out: h*g, [B,H,T,N]
    const float* __restrict__ Wh,    // [16,64,64]
    const float* __restrict__ bias,  // [16,64]
    const float* __restrict__ h0,    // [B,H,N]
    float* __restrict__ hfin)        // [B,H,N]
{
    const int bh = blockIdx.x;       // b*16 + h
    const int h = bh & 15;
    const int j = threadIdx.x;
    __shared__ float sh[64];

    // W_h[h][i][j] packed as f32x2 over i (column j in lane j)
    f32x2 w2[32];
    #pragma unroll
    for (int i = 0; i < 32; ++i) {
        w2[i].x = Wh[(h << 12) + ((2 * i) << 6) + j];
        w2[i].y = Wh[(h << 12) + ((2 * i + 1) << 6) + j];
    }
    const float bj = bias[(h << 6) + j];

    sh[j] = h0[(bh << 6) + j];
    __syncthreads();

    const float* px_p = preX + ((size_t)bh << 17);   // bh * T_*N_
    float* og_p = og + ((size_t)bh << 17);

    // fill the 8-deep ring buffer
    float pxb[8], gb[8];
    #pragma unroll
    for (int u = 0; u < 8; ++u) {
        pxb[u] = px_p[(u << 6) + j];
        gb[u]  = og_p[(u << 6) + j];
    }

    float hn = 0.f;
    for (int t0 = 0; t0 < T_; t0 += 8) {
        #pragma unroll
        for (int u = 0; u < 8; ++u) {
            const int t = t0 + u;
            const float px = pxb[u], g = gb[u];

            // issue prefetch for t+8 into this slot (clamped at tail)
            int tn = t + 8;
            if (tn > T_ - 1) tn = T_ - 1;
            pxb[u] = px_p[(tn << 6) + j];
            gb[u]  = og_p[(tn << 6) + j];

            // a_j = px + b_j + sum_i h_i * W_h[i][j], packed f32x2
            f32x2 a0 = {px + bj, 0.f};
            f32x2 a1 = {0.f, 0.f}, a2 = {0.f, 0.f}, a3 = {0.f, 0.f};
            #pragma unroll
            for (int i = 0; i < 8; ++i) {
                float4 hv0 = *(const float4*)&sh[(i << 3) + 0];
                float4 hv1 = *(const float4*)&sh[(i << 3) + 4];
                f32x2 h01 = {hv0.x, hv0.y}, h23 = {hv0.z, hv0.w};
                f32x2 h45 = {hv1.x, hv1.y}, h67 = {hv1.z, hv1.w};
                a0 = h01 * w2[(i << 2) + 0] + a0;
                a1 = h23 * w2[(i << 2) + 1] + a1;
                a2 = h45 * w2[(i << 2) + 2] + a2;
                a3 = h67 * w2[(i << 2) + 3] + a3;
            }
            float a = ((a0.x + a0.y) + (a1.x + a1.y)) +
                      ((a2.x + a2.y) + (a3.x + a3.y));
            hn = tanh_f(a);
            og_p[(t << 6) + j] = hn * g;

            // publish h_new (single wave: LDS pipe is in-order, reads above
            // were issued before this write; wave_barrier pins compiler order)
            __builtin_amdgcn_wave_barrier();
            sh[j] = hn;
            __builtin_amdgcn_wave_barrier();
        }
    }
    hfin[(bh << 6) + j] = hn;
}

// -------------------------------------------------------------------------
// K3: out = og @ W_out^T (M=8192, K=1024, N=1024), 128x128 tile, 8x8/thread.
// A is read from [B,H,T,N] layout with head-aware indexing.
// grid = (8 n-tiles, 64 m-tiles), block = 256
// -------------------------------------------------------------------------
__global__ __launch_bounds__(256) void gemm_out_kernel(
    const float* __restrict__ og,    // [B,H,T,N] == logical A[8192][1024]
    const float* __restrict__ Wout,  // [1024,1024]
    float* __restrict__ out)         // [8192,1024]
{
    __shared__ float As[16][132];
    __shared__ float Bs[16][132];

    const int tid = threadIdx.x;
    const int tx = tid & 15, ty = tid >> 4;
    const int m0 = blockIdx.y * 128;
    const int n0 = blockIdx.x * 128;
    const int lr = tid >> 1;          // 0..127
    const int lc = (tid & 1) << 3;    // 0 or 8

    const int m = m0 + lr;
    const int b = m >> 11, t = m & 2047;

    float acc[8][8] = {};

    for (int k0 = 0; k0 < 1024; k0 += 16) {
        const int e = k0 + lc;            // logical col in [0,1024)
        const int he = e >> 6, je = e & 63;
        const float* ap = og + ((((b << 4) + he) * 2048 + t) << 6) + je;
        float4 a0v = *(const float4*)(ap);
        float4 a1v = *(const float4*)(ap + 4);
        const float* bp = Wout + (size_t)(n0 + lr) * 1024 + e;
        float4 b0v = *(const float4*)(bp);
        float4 b1v = *(const float4*)(bp + 4);
        __syncthreads();
        As[lc + 0][lr] = a0v.x; As[lc + 1][lr] = a0v.y;
        As[lc + 2][lr] = a0v.z; As[lc + 3][lr] = a0v.w;
        As[lc + 4][lr] = a1v.x; As[lc + 5][lr] = a1v.y;
        As[lc + 6][lr] = a1v.z; As[lc + 7][lr] = a1v.w;
        Bs[lc + 0][lr] = b0v.x; Bs[lc + 1][lr] = b0v.y;
        Bs[lc + 2][lr] = b0v.z; Bs[lc + 3][lr] = b0v.w;
        Bs[lc + 4][lr] = b1v.x; Bs[lc + 5][lr] = b1v.y;
        Bs[lc + 6][lr] = b1v.z; Bs[lc + 7][lr] = b1v.w;
        __syncthreads();
        #pragma unroll
        for (int kk = 0; kk < 16; ++kk) {
            float4 x0 = *(const float4*)&As[kk][ty << 3];
            float4 x1 = *(const float4*)&As[kk][(ty << 3) + 4];
            float4 y0 = *(const float4*)&Bs[kk][tx << 3];
            float4 y1 = *(const float4*)&Bs[kk][(tx << 3) + 4];
            float ar[8] = {x0.x, x0.y, x0.z, x0.w, x1.x, x1.y, x1.z, x1.w};
            float br[8] = {y0.x, y0.y, y0.z, y0.w, y1.x, y1.y, y1.z, y1.w};
            #pragma unroll
            for (int r = 0; r < 8; ++r)
                #pragma unroll
                for (int c = 0; c < 8; ++c)
                    acc[r][c] = fmaf(ar[r], br[c], acc[r][c]);
        }
    }

    #pragma unroll
    for (int r = 0; r < 8; ++r) {
        int mm = m0 + (ty << 3) + r;
        float4 o0 = make_float4(acc[r][0], acc[r][1], acc[r][2], acc[r][3]);
        float4 o1 = make_float4(acc[r][4], acc[r][5], acc[r][6], acc[r][7]);
        *(float4*)(out + (size_t)mm * 1024 + n0 + (tx << 3)) = o0;
        *(float4*)(out + (size_t)mm * 1024 + n0 + (tx << 3) + 4) = o1;
    }
}

// -------------------------------------------------------------------------
extern "C" void kernel_launch(void* const* d_in, const int* in_sizes, int n_in,
                              void* d_out, int out_size, void* d_ws, size_t ws_size,
                              hipStream_t stream)
{
    const float* x    = (const float*)d_in[0];
    const float* h0   = (const float*)d_in[1];
    const float* Win  = (const float*)d_in[2];
    const float* Wx   = (const float*)d_in[3];
    const float* Wh   = (const float*)d_in[4];
    const float* bias = (const float*)d_in[5];
    const float* Wout = (const float*)d_in[6];

    float* out  = (float*)d_out;
    float* hfin = out + (size_t)BT_ * DIM_;      // h_final after main output

    float* preX = (float*)d_ws;                  // [B,H,T,N] 32 MB
    float* gate = preX + (size_t)BT_ * DIM_;     // [B,H,T,N] 32 MB (becomes h*g)

    gemm_in_kernel<<<dim3(32, 128), 256, 0, stream>>>(x, Win, Wx, preX, gate);
    scan_kernel<<<64, 64, 0, stream>>>(preX, gate, Wh, bias, h0, hfin);
    gemm_out_kernel<<<dim3(8, 64), 256, 0, stream>>>(gate, Wout, out);
}

// Round 3
// 871.040 us; speedup vs baseline: 1.9790x; 1.4028x over previous
//
#include <hip/hip_runtime.h>
#include <cstdint>

#define B_    4
#define T_    2048
#define DIM_  1024
#define H_    16
#define N_    64
#define BT_   8192

typedef float f32x2 __attribute__((ext_vector_type(2)));
typedef float f32x4 __attribute__((ext_vector_type(4)));
typedef short bf16x8 __attribute__((ext_vector_type(8)));
typedef unsigned short ushort_t;
typedef unsigned int uint32;

__device__ __forceinline__ float silu_f(float v) {
    return v / (1.f + __expf(-v));
}
__device__ __forceinline__ float tanh_f(float v) {
    return 1.f - 2.f / (__expf(2.f * v) + 1.f);
}
__device__ __forceinline__ ushort_t f2bf(float f) {
    uint32 u = __float_as_uint(f);
    return (ushort_t)((u + 0x7fffu + ((u >> 16) & 1u)) >> 16);   // RNE
}
// async global->LDS, 16B per lane; lds base must be wave-uniform
__device__ __forceinline__ void glds16(const void* g, void* l) {
    __builtin_amdgcn_global_load_lds(
        (const __attribute__((address_space(1))) void*)g,
        (__attribute__((address_space(3))) void*)l, 16, 0, 0);
}

// -------------------------------------------------------------------------
// K0: f32 -> bf16 conversion (grid covers n8 = n/8 elements of 8)
// -------------------------------------------------------------------------
__global__ __launch_bounds__(256) void cvt_kernel(
    const float* __restrict__ src, ushort_t* __restrict__ dst, int n8)
{
    int i = blockIdx.x * 256 + threadIdx.x;
    if (i >= n8) return;
    float4 a = ((const float4*)src)[i * 2];
    float4 b = ((const float4*)src)[i * 2 + 1];
    uint4 o;
    o.x = (uint32)f2bf(a.x) | ((uint32)f2bf(a.y) << 16);
    o.y = (uint32)f2bf(a.z) | ((uint32)f2bf(a.w) << 16);
    o.z = (uint32)f2bf(b.x) | ((uint32)f2bf(b.y) << 16);
    o.w = (uint32)f2bf(b.z) | ((uint32)f2bf(b.w) << 16);
    ((uint4*)dst)[i] = o;
}

// -------------------------------------------------------------------------
// K1: xz = X @ Win^T (M=8192,N=2048,K=1024) bf16 MFMA, 128x128 tile, BK=32.
// n-tiles 8..15 (gate half): silu -> pg hi-halves (bf16).
// n-tiles 0..7 (x half): silu -> LDS -> per-head @Wx MFMA -> pg lo-halves.
// grid = (16, 64), block = 256 (4 waves; wave w -> 64x64 quadrant)
// -------------------------------------------------------------------------
__global__ __launch_bounds__(256) void gemm_in_kernel(
    const ushort_t* __restrict__ xw,    // [8192][1024] bf16
    const ushort_t* __restrict__ Winb,  // [2048][1024] bf16
    const float*    __restrict__ Wx,    // [16][64][64] f32
    ushort_t*       __restrict__ pg)    // [B,H,T,N] x2: [2i]=px, [2i+1]=gate
{
    __shared__ __align__(16) ushort_t Ab[128 * 32];
    __shared__ __align__(16) ushort_t Bb[128 * 32];
    __shared__ __align__(16) ushort_t Sb[128][136];     // padded: 272B row
    __shared__ __align__(16) ushort_t WxT[2][64][72];   // transposed, padded

    const int tid  = threadIdx.x;
    const int wave = tid >> 6, lane = tid & 63;
    const int l15 = lane & 15, l4 = lane >> 4;
    const int bx = blockIdx.x;
    const int m0 = blockIdx.y * 128;
    const int n0 = bx * 128;
    const int wr = wave >> 1, wc = wave & 1;
    const bool xhalf = (bx < 8);

    if (xhalf) {
        // stage W_x transposed (WxT[h][j][i] = Wx[h][i][j]) as bf16
        for (int q = tid; q < 8192; q += 256) {
            int hh = q >> 12, rem = q & 4095, i = rem >> 6, j = rem & 63;
            WxT[hh][j][i] = f2bf(Wx[(((bx << 1) + hh) << 12) + (i << 6) + j]);
        }
    }

    const f32x4 zero4 = {0.f, 0.f, 0.f, 0.f};
    f32x4 acc[4][4];
    #pragma unroll
    for (int mi = 0; mi < 4; ++mi)
        #pragma unroll
        for (int ni = 0; ni < 4; ++ni)
            acc[mi][ni] = zero4;

    const int rowL = tid >> 2;           // 0..63
    const int chL  = tid & 3;
    const ushort_t* gA0 = xw   + (size_t)(m0 + rowL) * 1024 + (chL << 3);
    const ushort_t* gA1 = xw   + (size_t)(m0 + 64 + rowL) * 1024 + (chL << 3);
    const ushort_t* gB0 = Winb + (size_t)(n0 + rowL) * 1024 + (chL << 3);
    const ushort_t* gB1 = Winb + (size_t)(n0 + 64 + rowL) * 1024 + (chL << 3);
    ushort_t* lA0 = Ab + wave * 512;
    ushort_t* lA1 = Ab + 2048 + wave * 512;
    ushort_t* lB0 = Bb + wave * 512;
    ushort_t* lB1 = Bb + 2048 + wave * 512;

    for (int k0 = 0; k0 < 1024; k0 += 32) {
        __syncthreads();
        glds16(gA0 + k0, lA0);
        glds16(gA1 + k0, lA1);
        glds16(gB0 + k0, lB0);
        glds16(gB1 + k0, lB1);
        asm volatile("s_waitcnt vmcnt(0)");
        __syncthreads();
        bf16x8 aF[4], bF[4];
        #pragma unroll
        for (int mi = 0; mi < 4; ++mi)
            aF[mi] = *(const bf16x8*)&Ab[(wr * 64 + mi * 16 + l15) * 32 + l4 * 8];
        #pragma unroll
        for (int ni = 0; ni < 4; ++ni)
            bF[ni] = *(const bf16x8*)&Bb[(wc * 64 + ni * 16 + l15) * 32 + l4 * 8];
        #pragma unroll
        for (int mi = 0; mi < 4; ++mi)
            #pragma unroll
            for (int ni = 0; ni < 4; ++ni)
                acc[mi][ni] = __builtin_amdgcn_mfma_f32_16x16x32_bf16(
                    aF[mi], bF[ni], acc[mi][ni], 0, 0, 0);
    }

    if (!xhalf) {
        // gate half: silu -> bf16 -> pg hi halves
        #pragma unroll
        for (int mi = 0; mi < 4; ++mi)
            #pragma unroll
            for (int ni = 0; ni < 4; ++ni) {
                int col = n0 - 1024 + wc * 64 + ni * 16 + l15;
                int h = col >> 6, n = col & 63;
                #pragma unroll
                for (int r = 0; r < 4; ++r) {
                    int row = m0 + wr * 64 + mi * 16 + l4 * 4 + r;
                    int b = row >> 11, t = row & 2047;
                    size_t idx = ((size_t)((b << 4) + h) * 2048 + t) * 64 + n;
                    pg[idx * 2 + 1] = f2bf(silu_f(acc[mi][ni][r]));
                }
            }
    } else {
        // x half: stage S = silu(acc) to LDS bf16
        __syncthreads();
        #pragma unroll
        for (int mi = 0; mi < 4; ++mi)
            #pragma unroll
            for (int ni = 0; ni < 4; ++ni) {
                int col = wc * 64 + ni * 16 + l15;
                #pragma unroll
                for (int r = 0; r < 4; ++r) {
                    int row = wr * 64 + mi * 16 + l4 * 4 + r;
                    Sb[row][col] = f2bf(silu_f(acc[mi][ni][r]));
                }
            }
        __syncthreads();
        // per-head: px[128x64] = S_h[128x64] @ Wx[h][64x64]
        #pragma unroll
        for (int hh = 0; hh < 2; ++hh) {
            f32x4 acc2[2][4];
            #pragma unroll
            for (int mf = 0; mf < 2; ++mf)
                #pragma unroll
                for (int nf = 0; nf < 4; ++nf)
                    acc2[mf][nf] = zero4;
            #pragma unroll
            for (int ks = 0; ks < 2; ++ks) {
                bf16x8 a2[2], b2[4];
                #pragma unroll
                for (int mf = 0; mf < 2; ++mf)
                    a2[mf] = *(const bf16x8*)&Sb[wave * 32 + mf * 16 + l15]
                                                [hh * 64 + ks * 32 + l4 * 8];
                #pragma unroll
                for (int nf = 0; nf < 4; ++nf)
                    b2[nf] = *(const bf16x8*)&WxT[hh][nf * 16 + l15][ks * 32 + l4 * 8];
                #pragma unroll
                for (int mf = 0; mf < 2; ++mf)
                    #pragma unroll
                    for (int nf = 0; nf < 4; ++nf)
                        acc2[mf][nf] = __builtin_amdgcn_mfma_f32_16x16x32_bf16(
                            a2[mf], b2[nf], acc2[mf][nf], 0, 0, 0);
            }
            const int hg = (bx << 1) + hh;
            #pragma unroll
            for (int mf = 0; mf < 2; ++mf)
                #pragma unroll
                for (int nf = 0; nf < 4; ++nf) {
                    int j = nf * 16 + l15;
                    #pragma unroll
                    for (int r = 0; r < 4; ++r) {
                        int row = m0 + wave * 32 + mf * 16 + l4 * 4 + r;
                        int b = row >> 11, t = row & 2047;
                        size_t idx = ((size_t)((b << 4) + hg) * 2048 + t) * 64 + j;
                        pg[idx * 2] = f2bf(acc2[mf][nf][r]);
                    }
                }
        }
    }
}

// -------------------------------------------------------------------------
// K2: sequential Elman scan (structure unchanged from R1; now reads packed
// px/gate bf16 pairs -> 1 load/step, and writes og as bf16).
// grid = 64, block = 64
// -------------------------------------------------------------------------
__global__ __launch_bounds__(64) void scan_kernel(
    const uint32* __restrict__ pg,   // [B,H,T,N] packed: lo=px, hi=gate
    ushort_t* __restrict__ og,       // out bf16 [B,H,T,N]
    const float* __restrict__ Wh,
    const float* __restrict__ bias,
    const float* __restrict__ h0,
    float* __restrict__ hfin)
{
    const int bh = blockIdx.x;
    const int h = bh & 15;
    const int j = threadIdx.x;
    __shared__ float sh[64];

    f32x2 w2[32];
    #pragma unroll
    for (int i = 0; i < 32; ++i) {
        w2[i].x = Wh[(h << 12) + ((2 * i) << 6) + j];
        w2[i].y = Wh[(h << 12) + ((2 * i + 1) << 6) + j];
    }
    const float bj = bias[(h << 6) + j];

    sh[j] = h0[(bh << 6) + j];
    __syncthreads();

    const uint32* pg_p = pg + ((size_t)bh << 17);
    ushort_t* og_p = og + ((size_t)bh << 17);

    uint32 buf[8];
    #pragma unroll
    for (int u = 0; u < 8; ++u)
        buf[u] = pg_p[(u << 6) + j];

    float hn = 0.f;
    for (int t0 = 0; t0 < T_; t0 += 8) {
        #pragma unroll
        for (int u = 0; u < 8; ++u) {
            const int t = t0 + u;
            const uint32 v = buf[u];
            int tn = t + 8;
            if (tn > T_ - 1) tn = T_ - 1;
            buf[u] = pg_p[(tn << 6) + j];

            const float px = __uint_as_float(v << 16);
            const float g  = __uint_as_float(v & 0xffff0000u);

            f32x2 a0 = {px + bj, 0.f};
            f32x2 a1 = {0.f, 0.f}, a2 = {0.f, 0.f}, a3 = {0.f, 0.f};
            #pragma unroll
            for (int i = 0; i < 8; ++i) {
                float4 hv0 = *(const float4*)&sh[(i << 3) + 0];
                float4 hv1 = *(const float4*)&sh[(i << 3) + 4];
                f32x2 h01 = {hv0.x, hv0.y}, h23 = {hv0.z, hv0.w};
                f32x2 h45 = {hv1.x, hv1.y}, h67 = {hv1.z, hv1.w};
                a0 = h01 * w2[(i << 2) + 0] + a0;
                a1 = h23 * w2[(i << 2) + 1] + a1;
                a2 = h45 * w2[(i << 2) + 2] + a2;
                a3 = h67 * w2[(i << 2) + 3] + a3;
            }
            float a = ((a0.x + a0.y) + (a1.x + a1.y)) +
                      ((a2.x + a2.y) + (a3.x + a3.y));
            hn = tanh_f(a);
            og_p[(t << 6) + j] = f2bf(hn * g);

            __builtin_amdgcn_wave_barrier();
            sh[j] = hn;
            __builtin_amdgcn_wave_barrier();
        }
    }
    hfin[(bh << 6) + j] = hn;
}

// -------------------------------------------------------------------------
// K3: out = og @ Wout^T (M=8192,N=1024,K=1024) bf16 MFMA, 128x128, BK=32.
// A (og) is [B,H,T,N] bf16 with head-block column mapping.
// grid = (8, 64), block = 256
// -------------------------------------------------------------------------
__global__ __launch_bounds__(256) void gemm_out_kernel(
    const ushort_t* __restrict__ og,     // [B,H,T,N] bf16
    const ushort_t* __restrict__ Woutb,  // [1024][1024] bf16
    float* __restrict__ out)             // [8192][1024] f32
{
    __shared__ __align__(16) ushort_t Ab[128 * 32];
    __shared__ __align__(16) ushort_t Bb[128 * 32];

    const int tid  = threadIdx.x;
    const int wave = tid >> 6, lane = tid & 63;
    const int l15 = lane & 15, l4 = lane >> 4;
    const int m0 = blockIdx.y * 128;
    const int n0 = blockIdx.x * 128;
    const int wr = wave >> 1, wc = wave & 1;

    const f32x4 zero4 = {0.f, 0.f, 0.f, 0.f};
    f32x4 acc[4][4];
    #pragma unroll
    for (int mi = 0; mi < 4; ++mi)
        #pragma unroll
        for (int ni = 0; ni < 4; ++ni)
            acc[mi][ni] = zero4;

    const int rowL = tid >> 2;
    const int chL  = tid & 3;
    const int mA0 = m0 + rowL,       bA0 = mA0 >> 11, tA0 = mA0 & 2047;
    const int mA1 = m0 + 64 + rowL,  bA1 = mA1 >> 11, tA1 = mA1 & 2047;
    const ushort_t* gB0 = Woutb + (size_t)(n0 + rowL) * 1024 + (chL << 3);
    const ushort_t* gB1 = Woutb + (size_t)(n0 + 64 + rowL) * 1024 + (chL << 3);
    ushort_t* lA0 = Ab + wave * 512;
    ushort_t* lA1 = Ab + 2048 + wave * 512;
    ushort_t* lB0 = Bb + wave * 512;
    ushort_t* lB1 = Bb + 2048 + wave * 512;

    for (int k0 = 0; k0 < 1024; k0 += 32) {
        const int he = k0 >> 6, ke = (k0 & 63) + (chL << 3);
        const ushort_t* gA0 = og + ((size_t)((bA0 << 4) + he) * 2048 + tA0) * 64 + ke;
        const ushort_t* gA1 = og + ((size_t)((bA1 << 4) + he) * 2048 + tA1) * 64 + ke;
        __syncthreads();
        glds16(gA0, lA0);
        glds16(gA1, lA1);
        glds16(gB0 + k0, lB0);
        glds16(gB1 + k0, lB1);
        asm volatile("s_waitcnt vmcnt(0)");
        __syncthreads();
        bf16x8 aF[4], bF[4];
        #pragma unroll
        for (int mi = 0; mi < 4; ++mi)
            aF[mi] = *(const bf16x8*)&Ab[(wr * 64 + mi * 16 + l15) * 32 + l4 * 8];
        #pragma unroll
        for (int ni = 0; ni < 4; ++ni)
            bF[ni] = *(const bf16x8*)&Bb[(wc * 64 + ni * 16 + l15) * 32 + l4 * 8];
        #pragma unroll
        for (int mi = 0; mi < 4; ++mi)
            #pragma unroll
            for (int ni = 0; ni < 4; ++ni)
                acc[mi][ni] = __builtin_amdgcn_mfma_f32_16x16x32_bf16(
                    aF[mi], bF[ni], acc[mi][ni], 0, 0, 0);
    }

    #pragma unroll
    for (int mi = 0; mi < 4; ++mi)
        #pragma unroll
        for (int ni = 0; ni < 4; ++ni) {
            int d = n0 + wc * 64 + ni * 16 + l15;
            #pragma unroll
            for (int r = 0; r < 4; ++r) {
                int row = m0 + wr * 64 + mi * 16 + l4 * 4 + r;
                out[(size_t)row * 1024 + d] = acc[mi][ni][r];
            }
        }
}

// -------------------------------------------------------------------------
extern "C" void kernel_launch(void* const* d_in, const int* in_sizes, int n_in,
                              void* d_out, int out_size, void* d_ws, size_t ws_size,
                              hipStream_t stream)
{
    const float* x    = (const float*)d_in[0];
    const float* h0   = (const float*)d_in[1];
    const float* Win  = (const float*)d_in[2];
    const float* Wx   = (const float*)d_in[3];
    const float* Wh   = (const float*)d_in[4];
    const float* bias = (const float*)d_in[5];
    const float* Wout = (const float*)d_in[6];

    float* out  = (float*)d_out;
    float* hfin = out + (size_t)BT_ * DIM_;

    // ws layout (54 MB total):
    char* ws = (char*)d_ws;
    ushort_t* pg    = (ushort_t*)(ws);                      // 32 MB packed px/gate
    ushort_t* xw    = (ushort_t*)(ws + 33554432);           // 16 MB bf16 x
    ushort_t* ogb   = xw;                                   // og aliases xw (dead after K1)
    ushort_t* Winb  = (ushort_t*)(ws + 50331648);           // 4 MB
    ushort_t* Woutb = (ushort_t*)(ws + 54525952);           // 2 MB

    cvt_kernel<<<4096, 256, 0, stream>>>(x, xw, 1048576);
    cvt_kernel<<<1024, 256, 0, stream>>>(Win, Winb, 262144);
    cvt_kernel<<<512, 256, 0, stream>>>(Wout, Woutb, 131072);

    gemm_in_kernel<<<dim3(16, 64), 256, 0, stream>>>(xw, Winb, Wx, pg);
    scan_kernel<<<64, 64, 0, stream>>>((const uint32*)pg, ogb, Wh, bias, h0, hfin);
    gemm_out_kernel<<<dim3(8, 64), 256, 0, stream>>>(ogb, Woutb, out);
}